// Round 5
// baseline (17.438 us; speedup 1.0000x reference)
//
#include <hip/hip_runtime.h>

typedef float v2f __attribute__((ext_vector_type(2)));

__device__ __forceinline__ v2f vfma(v2f a, v2f b, v2f c) {
    return __builtin_elementwise_fma(a, b, c);
}
__device__ __forceinline__ v2f splat(float x) { v2f r; r.x = x; r.y = x; return r; }

__device__ __forceinline__ float rcp_fast(float x) { return __builtin_amdgcn_rcpf(x); }

// tanh(x) = (1 - e^{-2x}) / (1 + e^{-2x}); all inputs here bounded |x| < ~6.
__device__ __forceinline__ float tanh_fast(float x) {
    float e = __expf(-2.0f * x);
    return (1.0f - e) * rcp_fast(1.0f + e);
}

__device__ __forceinline__ void cmul(float ar, float ai, float br, float bi,
                                     float& cr, float& ci) {
    cr = ar * br - ai * bi;
    ci = ar * bi + ai * br;
}

// ---- packed butterfly gates ----
// State: 16 complex amps packed by index: sr[k] = (Re psi[2k], Re psi[2k+1]), si likewise.
// Qubit w has stride R = 8>>w. For R>=2 the butterfly pairs v2f index k with k+K, K=R/2.
template<int K>
__device__ __forceinline__ void rx_gate_p(v2f (&sr)[8], v2f (&si)[8], float s, float c) {
    v2f cs = splat(c), ss = splat(s);
    #pragma unroll
    for (int k = 0; k < 8; ++k) {
        if ((k & K) == 0) {
            const int e = k + K;
            v2f ar = sr[k], ai = si[k], br = sr[e], bi = si[e];
            sr[k] = vfma(cs, ar,  ss * bi);
            si[k] = vfma(cs, ai, -(ss * br));
            sr[e] = vfma(cs, br,  ss * ai);
            si[e] = vfma(cs, bi, -(ss * ar));
        }
    }
}
template<int K>
__device__ __forceinline__ void ry_gate_p(v2f (&sr)[8], v2f (&si)[8], float s, float c) {
    v2f cs = splat(c), ss = splat(s);
    #pragma unroll
    for (int k = 0; k < 8; ++k) {
        if ((k & K) == 0) {
            const int e = k + K;
            v2f ar = sr[k], ai = si[k], br = sr[e], bi = si[e];
            sr[k] = vfma(cs, ar, -(ss * br));
            si[k] = vfma(cs, ai, -(ss * bi));
            sr[e] = vfma(ss, ar,  cs * br);
            si[e] = vfma(ss, ai,  cs * bi);
        }
    }
}
// Qubit 3 (R=1): pairs live inside one v2f -> .yx swizzle (op_sel), per-lane signs.
__device__ __forceinline__ void rx_gate_1(v2f (&sr)[8], v2f (&si)[8], float s, float c) {
    v2f cs = splat(c), ss = splat(s);
    #pragma unroll
    for (int k = 0; k < 8; ++k) {
        v2f r = sr[k], i = si[k];
        sr[k] = vfma(cs, r,  ss * i.yx);
        si[k] = vfma(cs, i, -(ss * r.yx));
    }
}
__device__ __forceinline__ void ry_gate_1(v2f (&sr)[8], v2f (&si)[8], float s, float c) {
    v2f cs = splat(c);
    v2f sn; sn.x = -s; sn.y = s;
    #pragma unroll
    for (int k = 0; k < 8; ++k) {
        v2f r = sr[k], i = si[k];
        sr[k] = vfma(cs, r, sn * r.yx);
        si[k] = vfma(cs, i, sn * i.yx);
    }
}

__global__ void __launch_bounds__(256)
qpinn_kernel(const float* __restrict__ xy,
             const float* __restrict__ W1, const float* __restrict__ b1,
             const float* __restrict__ W2, const float* __restrict__ b2,
             const float* __restrict__ W3, const float* __restrict__ b3,
             const float* __restrict__ W4, const float* __restrict__ b4,
             float* __restrict__ out, int B)
{
    // Phase-structured for ILP: the angle network does not depend on the
    // quantum state, so ALL transcendental-heavy work is hoisted into flat
    // independent batches (40 preacts -> 40 tanh -> 80 sincos), then the
    // gate phase is pure VALU with wide ILP. Occupancy is grid-limited at
    // 2 waves/SIMD, so the extra ~120 live VGPRs are free.
    int tid = blockIdx.x * blockDim.x + threadIdx.x;
    int t = tid < B ? tid : B - 1;   // uniform CF; B is a multiple of 256 anyway

    float2 P = reinterpret_cast<const float2*>(xy)[t];
    float x = P.x, y = P.y;

    // ---- Phase 1: h = tanh(xy @ W1 + b1) ----
    float pre1[16];
    #pragma unroll
    for (int j = 0; j < 16; ++j)
        pre1[j] = fmaf(x, W1[j], fmaf(y, W1[16 + j], b1[j]));
    float h[16];
    #pragma unroll
    for (int j = 0; j < 16; ++j)
        h[j] = tanh_fast(pre1[j]);

    // ---- Phase 2: all 40 angle pre-activations (20 independent v2f chains) ----
    float ang[40];
    #pragma unroll
    for (int j2 = 0; j2 < 20; ++j2) {
        const int j = 2 * j2;
        v2f acc; acc.x = b2[j]; acc.y = b2[j + 1];
        #pragma unroll
        for (int k = 0; k < 16; ++k) {
            v2f w; w.x = W2[k * 40 + j]; w.y = W2[k * 40 + j + 1];
            acc = vfma(splat(h[k]), w, acc);
        }
        ang[j] = acc.x; ang[j + 1] = acc.y;
    }

    // ---- Phase 3+4: 40 tanh, then 80 sincos, all independent ----
    const float REV = 0.5f * 0.15915494309189535f; // (t/2) in revolutions per unit t
    float sn[40], cn[40];
    #pragma unroll
    for (int m = 0; m < 40; ++m)
        ang[m] = tanh_fast(ang[m]) * REV;
    #pragma unroll
    for (int m = 0; m < 40; ++m) {
        sn[m] = __builtin_amdgcn_sinf(ang[m]);
        cn[m] = __builtin_amdgcn_cosf(ang[m]);
    }

    // ---- Phase 5: initial state (tensor power) ----
    float sa = __builtin_amdgcn_sinf(0.25f * x), ca = __builtin_amdgcn_cosf(0.25f * x);
    float sb = __builtin_amdgcn_sinf(0.25f * y), cb = __builtin_amdgcn_cosf(0.25f * y);
    const float is2 = 0.70710678118654752f;
    float m0 = is2 * (ca - sa), m1 = is2 * (ca + sa);
    float u0r = m0 * cb, u0i = -m0 * sb;
    float u1r = m1 * cb, u1i =  m1 * sb;

    float p2r, p2i, p3r, p3i, p4r, p4i;
    float q2r, q2i, q3r, q3i, q4r, q4i;
    cmul(u0r, u0i, u0r, u0i, p2r, p2i);
    cmul(p2r, p2i, u0r, u0i, p3r, p3i);
    cmul(p3r, p3i, u0r, u0i, p4r, p4i);
    cmul(u1r, u1i, u1r, u1i, q2r, q2i);
    cmul(q2r, q2i, u1r, u1i, q3r, q3i);
    cmul(q3r, q3i, u1r, u1i, q4r, q4i);

    float trr[5], tii[5];
    trr[0] = p4r; tii[0] = p4i;
    cmul(p3r, p3i, u1r, u1i, trr[1], tii[1]);
    cmul(p2r, p2i, q2r, q2i, trr[2], tii[2]);
    cmul(u0r, u0i, q3r, q3i, trr[3], tii[3]);
    trr[4] = q4r; tii[4] = q4i;

    constexpr int pc[16] = {0,1,1,2, 1,2,2,3, 1,2,2,3, 2,3,3,4};
    v2f sr[8], si[8];
    #pragma unroll
    for (int k = 0; k < 8; ++k) {
        sr[k].x = trr[pc[2*k]];   sr[k].y = trr[pc[2*k+1]];
        si[k].x = tii[pc[2*k]];   si[k].y = tii[pc[2*k+1]];
    }

    // ---- Phase 6: gate phase (pure VALU) ----
    #pragma unroll
    for (int l = 0; l < 5; ++l) {
        const int o = l * 8;
        rx_gate_p<4>(sr, si, sn[o + 0], cn[o + 0]);
        ry_gate_p<4>(sr, si, sn[o + 4], cn[o + 4]);
        rx_gate_p<2>(sr, si, sn[o + 1], cn[o + 1]);
        ry_gate_p<2>(sr, si, sn[o + 5], cn[o + 5]);
        rx_gate_p<1>(sr, si, sn[o + 2], cn[o + 2]);
        ry_gate_p<1>(sr, si, sn[o + 6], cn[o + 6]);
        rx_gate_1(sr, si, sn[o + 3], cn[o + 3]);
        ry_gate_1(sr, si, sn[o + 7], cn[o + 7]);

        // CZ ring: sign -1 at basis states {3,6,9,12}
        sr[1].y = -sr[1].y;  si[1].y = -si[1].y;   // state 3
        sr[3].x = -sr[3].x;  si[3].x = -si[3].x;   // state 6
        sr[4].y = -sr[4].y;  si[4].y = -si[4].y;   // state 9
        sr[6].x = -sr[6].x;  si[6].x = -si[6].x;   // state 12
    }

    // ---- Phase 7: measurement ----
    float ev[8], ov[8];
    #pragma unroll
    for (int k = 0; k < 8; ++k) {
        v2f pz = vfma(sr[k], sr[k], si[k] * si[k]);
        ev[k] = pz.x + pz.y;   // both lanes same sign for qubits 0-2
        ov[k] = pz.x - pz.y;   // lane sign split for qubit 3
    }
    float q0 = 0.f, q1 = 0.f, q2 = 0.f, q3 = 0.f;
    #pragma unroll
    for (int k = 0; k < 8; ++k) {
        q0 += (k & 4) ? -ev[k] : ev[k];
        q1 += (k & 2) ? -ev[k] : ev[k];
        q2 += (k & 1) ? -ev[k] : ev[k];
        q3 += ov[k];
    }

    // ---- head: out = tanh(q @ W3 + b3) @ W4 + b4 ; W3 (4,8) row-major ----
    float g8[8];
    #pragma unroll
    for (int j = 0; j < 8; ++j) {
        float g = b3[j];
        g = fmaf(q0, W3[j],      g);
        g = fmaf(q1, W3[8 + j],  g);
        g = fmaf(q2, W3[16 + j], g);
        g = fmaf(q3, W3[24 + j], g);
        g8[j] = g;
    }
    float oacc = b4[0];
    #pragma unroll
    for (int j = 0; j < 8; ++j)
        oacc = fmaf(tanh_fast(g8[j]), W4[j], oacc);
    out[t] = oacc;
}

extern "C" void kernel_launch(void* const* d_in, const int* in_sizes, int n_in,
                              void* d_out, int out_size, void* d_ws, size_t ws_size,
                              hipStream_t stream) {
    const float* xy = (const float*)d_in[0];
    const float* W1 = (const float*)d_in[1];
    const float* b1 = (const float*)d_in[2];
    const float* W2 = (const float*)d_in[3];
    const float* b2 = (const float*)d_in[4];
    const float* W3 = (const float*)d_in[5];
    const float* b3 = (const float*)d_in[6];
    const float* W4 = (const float*)d_in[7];
    const float* b4 = (const float*)d_in[8];
    float* out = (float*)d_out;

    const int B = in_sizes[0] / 2;
    const int block = 256;
    const int grid = (B + block - 1) / block;
    qpinn_kernel<<<grid, block, 0, stream>>>(xy, W1, b1, W2, b2, W3, b3, W4, b4, out, B);
}

// Round 6
// 16.414 us; speedup vs baseline: 1.0624x; 1.0624x over previous
//
#include <hip/hip_runtime.h>

typedef float v2f __attribute__((ext_vector_type(2)));

__device__ __forceinline__ v2f vfma(v2f a, v2f b, v2f c) {
    return __builtin_elementwise_fma(a, b, c);
}
__device__ __forceinline__ v2f splat(float x) { v2f r; r.x = x; r.y = x; return r; }

__device__ __forceinline__ float rcp_fast(float x) { return __builtin_amdgcn_rcpf(x); }

// tanh(x) = (1 - e^{-2x}) / (1 + e^{-2x}); all inputs here bounded |x| < ~6.
__device__ __forceinline__ float tanh_fast(float x) {
    float e = __expf(-2.0f * x);
    return (1.0f - e) * rcp_fast(1.0f + e);
}

__device__ __forceinline__ void cmul(float ar, float ai, float br, float bi,
                                     float& cr, float& ci) {
    cr = ar * br - ai * bi;
    ci = ar * bi + ai * br;
}

// ---- packed butterfly gates ----
// State: 16 complex amps packed by index: sr[k] = (Re psi[2k], Re psi[2k+1]), si likewise.
// Qubit w has stride R = 8>>w. For R>=2 the butterfly pairs v2f index k with k+K, K=R/2.
template<int K>
__device__ __forceinline__ void rx_gate_p(v2f (&sr)[8], v2f (&si)[8], float s, float c) {
    v2f cs = splat(c), ss = splat(s);
    #pragma unroll
    for (int k = 0; k < 8; ++k) {
        if ((k & K) == 0) {
            const int e = k + K;
            v2f ar = sr[k], ai = si[k], br = sr[e], bi = si[e];
            sr[k] = vfma(cs, ar,  ss * bi);
            si[k] = vfma(cs, ai, -(ss * br));
            sr[e] = vfma(cs, br,  ss * ai);
            si[e] = vfma(cs, bi, -(ss * ar));
        }
    }
}
template<int K>
__device__ __forceinline__ void ry_gate_p(v2f (&sr)[8], v2f (&si)[8], float s, float c) {
    v2f cs = splat(c), ss = splat(s);
    #pragma unroll
    for (int k = 0; k < 8; ++k) {
        if ((k & K) == 0) {
            const int e = k + K;
            v2f ar = sr[k], ai = si[k], br = sr[e], bi = si[e];
            sr[k] = vfma(cs, ar, -(ss * br));
            si[k] = vfma(cs, ai, -(ss * bi));
            sr[e] = vfma(ss, ar,  cs * br);
            si[e] = vfma(ss, ai,  cs * bi);
        }
    }
}
// Qubit 3 (R=1): pairs live inside one v2f -> .yx swizzle (op_sel), per-lane signs.
__device__ __forceinline__ void rx_gate_1(v2f (&sr)[8], v2f (&si)[8], float s, float c) {
    v2f cs = splat(c), ss = splat(s);
    #pragma unroll
    for (int k = 0; k < 8; ++k) {
        v2f r = sr[k], i = si[k];
        sr[k] = vfma(cs, r,  ss * i.yx);
        si[k] = vfma(cs, i, -(ss * r.yx));
    }
}
__device__ __forceinline__ void ry_gate_1(v2f (&sr)[8], v2f (&si)[8], float s, float c) {
    v2f cs = splat(c);
    v2f sn; sn.x = -s; sn.y = s;
    #pragma unroll
    for (int k = 0; k < 8; ++k) {
        v2f r = sr[k], i = si[k];
        sr[k] = vfma(cs, r, sn * r.yx);
        si[k] = vfma(cs, i, sn * i.yx);
    }
}

__global__ void __launch_bounds__(256)
qpinn_kernel(const float* __restrict__ xy,
             const float* __restrict__ W1, const float* __restrict__ b1,
             const float* __restrict__ W2, const float* __restrict__ b2,
             const float* __restrict__ W3, const float* __restrict__ b3,
             const float* __restrict__ W4, const float* __restrict__ b4,
             float* __restrict__ out, int B)
{
    // EXPERIMENT (R6): identical math to R2/R5 but the 5-layer loop is a REAL
    // loop (#pragma unroll 1). Code size drops ~4x (one layer body ~3 KB
    // instead of 5 unrolled copies) to test whether the flat ~17 us across
    // R2/R4/R5 is instruction-fetch-bound on fully-unrolled straight-line
    // code rather than VALU-bound.
    int tid = blockIdx.x * blockDim.x + threadIdx.x;
    int t = tid < B ? tid : B - 1;   // uniform CF

    float2 P = reinterpret_cast<const float2*>(xy)[t];
    float x = P.x, y = P.y;

    // ---- front MLP: h = tanh(xy @ W1 + b1), W1 (2,16) row-major ----
    float h[16];
    #pragma unroll
    for (int j = 0; j < 16; ++j)
        h[j] = tanh_fast(fmaf(x, W1[j], fmaf(y, W1[16 + j], b1[j])));

    // ---- initial state: tensor power. psi[d] = u0^(4-k) u1^k, k = popcount(d) ----
    float sa = __builtin_amdgcn_sinf(0.25f * x), ca = __builtin_amdgcn_cosf(0.25f * x);
    float sb = __builtin_amdgcn_sinf(0.25f * y), cb = __builtin_amdgcn_cosf(0.25f * y);
    const float is2 = 0.70710678118654752f;
    float m0 = is2 * (ca - sa), m1 = is2 * (ca + sa);
    float u0r = m0 * cb, u0i = -m0 * sb;
    float u1r = m1 * cb, u1i =  m1 * sb;

    float p2r, p2i, p3r, p3i, p4r, p4i;
    float q2r, q2i, q3r, q3i, q4r, q4i;
    cmul(u0r, u0i, u0r, u0i, p2r, p2i);
    cmul(p2r, p2i, u0r, u0i, p3r, p3i);
    cmul(p3r, p3i, u0r, u0i, p4r, p4i);
    cmul(u1r, u1i, u1r, u1i, q2r, q2i);
    cmul(q2r, q2i, u1r, u1i, q3r, q3i);
    cmul(q3r, q3i, u1r, u1i, q4r, q4i);

    float trr[5], tii[5];
    trr[0] = p4r; tii[0] = p4i;
    cmul(p3r, p3i, u1r, u1i, trr[1], tii[1]);
    cmul(p2r, p2i, q2r, q2i, trr[2], tii[2]);
    cmul(u0r, u0i, q3r, q3i, trr[3], tii[3]);
    trr[4] = q4r; tii[4] = q4i;

    constexpr int pc[16] = {0,1,1,2, 1,2,2,3, 1,2,2,3, 2,3,3,4};
    v2f sr[8], si[8];
    #pragma unroll
    for (int k = 0; k < 8; ++k) {
        sr[k].x = trr[pc[2*k]];   sr[k].y = trr[pc[2*k+1]];
        si[k].x = tii[pc[2*k]];   si[k].y = tii[pc[2*k+1]];
    }

    const float REV = 0.5f * 0.15915494309189535f; // (t/2) in revolutions per unit t

    // ---- layers: REAL loop, body emitted once ----
    #pragma unroll 1
    for (int l = 0; l < 5; ++l) {
        // angles: a8[m] = tanh(h @ W2[:, l*8+m] + b2[l*8+m]); W2 (16,40) row-major.
        const float* W2c = W2 + l * 8;
        const float* b2c = b2 + l * 8;
        float a8[8];
        #pragma unroll
        for (int m2 = 0; m2 < 4; ++m2) {
            const int j = 2 * m2;
            v2f acc; acc.x = b2c[j]; acc.y = b2c[j + 1];
            #pragma unroll
            for (int k = 0; k < 16; ++k) {
                v2f w; w.x = W2c[k * 40 + j]; w.y = W2c[k * 40 + j + 1];
                acc = vfma(splat(h[k]), w, acc);
            }
            a8[j]     = tanh_fast(acc.x) * REV;
            a8[j + 1] = tanh_fast(acc.y) * REV;
        }
        float sn[8], cn[8];
        #pragma unroll
        for (int m = 0; m < 8; ++m) {
            sn[m] = __builtin_amdgcn_sinf(a8[m]);
            cn[m] = __builtin_amdgcn_cosf(a8[m]);
        }

        rx_gate_p<4>(sr, si, sn[0], cn[0]);
        ry_gate_p<4>(sr, si, sn[4], cn[4]);
        rx_gate_p<2>(sr, si, sn[1], cn[1]);
        ry_gate_p<2>(sr, si, sn[5], cn[5]);
        rx_gate_p<1>(sr, si, sn[2], cn[2]);
        ry_gate_p<1>(sr, si, sn[6], cn[6]);
        rx_gate_1(sr, si, sn[3], cn[3]);
        ry_gate_1(sr, si, sn[7], cn[7]);

        // CZ ring: sign -1 at basis states {3,6,9,12}
        sr[1].y = -sr[1].y;  si[1].y = -si[1].y;   // state 3
        sr[3].x = -sr[3].x;  si[3].x = -si[3].x;   // state 6
        sr[4].y = -sr[4].y;  si[4].y = -si[4].y;   // state 9
        sr[6].x = -sr[6].x;  si[6].x = -si[6].x;   // state 12
    }

    // ---- measurement ----
    float ev[8], ov[8];
    #pragma unroll
    for (int k = 0; k < 8; ++k) {
        v2f pz = vfma(sr[k], sr[k], si[k] * si[k]);
        ev[k] = pz.x + pz.y;   // both lanes same sign for qubits 0-2
        ov[k] = pz.x - pz.y;   // lane sign split for qubit 3
    }
    float q0 = 0.f, q1 = 0.f, q2 = 0.f, q3 = 0.f;
    #pragma unroll
    for (int k = 0; k < 8; ++k) {
        q0 += (k & 4) ? -ev[k] : ev[k];
        q1 += (k & 2) ? -ev[k] : ev[k];
        q2 += (k & 1) ? -ev[k] : ev[k];
        q3 += ov[k];
    }

    // ---- head: out = tanh(q @ W3 + b3) @ W4 + b4 ; W3 (4,8) row-major ----
    float g8[8];
    #pragma unroll
    for (int j = 0; j < 8; ++j) {
        float g = b3[j];
        g = fmaf(q0, W3[j],      g);
        g = fmaf(q1, W3[8 + j],  g);
        g = fmaf(q2, W3[16 + j], g);
        g = fmaf(q3, W3[24 + j], g);
        g8[j] = g;
    }
    float oacc = b4[0];
    #pragma unroll
    for (int j = 0; j < 8; ++j)
        oacc = fmaf(tanh_fast(g8[j]), W4[j], oacc);
    out[t] = oacc;
}

extern "C" void kernel_launch(void* const* d_in, const int* in_sizes, int n_in,
                              void* d_out, int out_size, void* d_ws, size_t ws_size,
                              hipStream_t stream) {
    const float* xy = (const float*)d_in[0];
    const float* W1 = (const float*)d_in[1];
    const float* b1 = (const float*)d_in[2];
    const float* W2 = (const float*)d_in[3];
    const float* b2 = (const float*)d_in[4];
    const float* W3 = (const float*)d_in[5];
    const float* b3 = (const float*)d_in[6];
    const float* W4 = (const float*)d_in[7];
    const float* b4 = (const float*)d_in[8];
    float* out = (float*)d_out;

    const int B = in_sizes[0] / 2;
    const int block = 256;
    const int grid = (B + block - 1) / block;
    qpinn_kernel<<<grid, block, 0, stream>>>(xy, W1, b1, W2, b2, W3, b3, W4, b4, out, B);
}